// Round 2
// baseline (1058.692 us; speedup 1.0000x reference)
//
#include <hip/hip_runtime.h>
#include <math.h>

// ---------------- kernels ----------------

__global__ void zero_kernel(float* p, int n) {
    int i = blockIdx.x * blockDim.x + threadIdx.x;
    if (i < n) p[i] = 0.f;
}

// weighted degree (for norm) + integer in-degree count (for CSR)
__global__ void deg_kernel(const int* ei, const float* ew,
                           float* degw, int* cnt, int E) {
    int i = blockIdx.x * blockDim.x + threadIdx.x;
    if (i >= E) return;
    int dst = ei[E + i];
    atomicAdd(&degw[dst], ew[i]);
    atomicAdd(&cnt[dst], 1);
}

// degw -> dis = deg>0 ? 1/sqrt(deg) : 0   (in place)
__global__ void dis_kernel(float* degw, int n) {
    int i = blockIdx.x * blockDim.x + threadIdx.x;
    if (i < n) {
        float d = degw[i];
        degw[i] = (d > 0.f) ? (1.0f / sqrtf(d)) : 0.f;
    }
}

// --- 3-kernel exclusive scan of cnt -> row_ptr ---
__global__ void scan1(const int* cnt, int* row_ptr, int* blockSums, int n) {
    __shared__ int sh[1024];
    int i = blockIdx.x * 1024 + threadIdx.x;
    int v = (i < n) ? cnt[i] : 0;
    sh[threadIdx.x] = v;
    __syncthreads();
    for (int off = 1; off < 1024; off <<= 1) {
        int t = 0;
        if (threadIdx.x >= off) t = sh[threadIdx.x - off];
        __syncthreads();
        sh[threadIdx.x] += t;
        __syncthreads();
    }
    if (i < n) row_ptr[i] = sh[threadIdx.x] - v;  // exclusive within block
    if (threadIdx.x == 1023) blockSums[blockIdx.x] = sh[1023];
}

__global__ void scan2(int* blockSums, int nb) {
    if (threadIdx.x == 0 && blockIdx.x == 0) {
        int run = 0;
        for (int i = 0; i < nb; i++) { int v = blockSums[i]; blockSums[i] = run; run += v; }
    }
}

__global__ void scan3(int* row_ptr, int* cursor, const int* blockSums, int n, int E) {
    int i = blockIdx.x * 1024 + threadIdx.x;
    if (i < n) {
        int v = row_ptr[i] + blockSums[blockIdx.x];
        row_ptr[i] = v;
        cursor[i] = v;
    }
    if (i == 0) row_ptr[n] = E;
}

// place edges into CSR (by dst), computing norm on the fly
__global__ void place_kernel(const int* ei, const float* ew, const float* dis,
                             int* cursor, int* csr_src, float* csr_w, int E) {
    int i = blockIdx.x * blockDim.x + threadIdx.x;
    if (i >= E) return;
    int s = ei[i];
    int d = ei[E + i];
    float nrm = dis[s] * ew[i] * dis[d];
    int pos = atomicAdd(&cursor[d], 1);
    csr_src[pos] = s;
    csr_w[pos] = nrm;
}

// conv1 t=0 transform: Q = x*w_init   (48 ch per node)
__global__ void conv1_init(const float* x, const float* w_init, float* Q, int n) {
    unsigned t = blockIdx.x * blockDim.x + threadIdx.x;
    if (t >= (unsigned)n * 48u) return;
    unsigned node = t / 48u, j = t % 48u;
    Q[t] = x[node] * w_init[j];
}

// per-stack 16x16 dense transform: Q[n,k,:] = P[n,k,:] @ W[k]
__global__ void transform48(const float* P, const float* W, float* Q, int n) {
    __shared__ float sW[3 * 16 * 16];
    for (int i = threadIdx.x; i < 768; i += blockDim.x) sW[i] = W[i];
    __syncthreads();
    unsigned t = blockIdx.x * blockDim.x + threadIdx.x;
    if (t >= (unsigned)n * 48u) return;
    unsigned node = t / 48u, j = t % 48u, k = j / 16u, o = j % 16u;
    const float* prow = &P[node * 48u + k * 16u];
    const float* wk = &sW[k * 256u + o];
    float acc = 0.f;
#pragma unroll
    for (int i = 0; i < 16; i++) acc += prow[i] * wk[i * 16];
    Q[t] = acc;
}

// gather-aggregate 48 channels with fused root+relu:
// P[n,c] = relu( sum_e Q[src_e,c]*w_e + x[n]*w_root[c] + b[c] )
// one wave per node, lanes 0..47 own channels
__global__ void agg48(const float* Q, const float* x, const float* w_root,
                      const float* w_b, const int* row_ptr,
                      const int* csr_src, const float* csr_w, float* P, int n) {
    int wid = (int)((blockIdx.x * blockDim.x + threadIdx.x) >> 6);
    int lane = threadIdx.x & 63;
    if (wid >= n) return;
    int start = row_ptr[wid], end = row_ptr[wid + 1];
    if (lane < 48) {
        float acc = 0.f;
        for (int p = start; p < end; p++) {
            int s = csr_src[p];
            float w = csr_w[p];
            acc += Q[(unsigned)s * 48u + lane] * w;
        }
        float v = acc + x[wid] * w_root[lane] + w_b[lane];
        P[(unsigned)wid * 48u + lane] = fmaxf(v, 0.f);
    }
}

// BN stats: accumulate sum and sumsq of h = mean_k(P) per channel
__global__ void bn_stats(const float* P, float* acc, int n) {
    int tid = threadIdx.x;
    int c = tid & 15;
    int rowSlot = (int)((blockIdx.x * blockDim.x + tid) >> 4);
    int rowStride = (int)((gridDim.x * blockDim.x) >> 4);
    float s1 = 0.f, s2 = 0.f;
    for (int r = rowSlot; r < n; r += rowStride) {
        const float* row = &P[(unsigned)r * 48u];
        float h = (row[c] + row[16 + c] + row[32 + c]) * (1.f / 3.f);
        s1 += h;
        s2 += h * h;
    }
    __shared__ float sh[256];
    sh[tid] = s1; __syncthreads();
    for (int off = 128; off >= 16; off >>= 1) { if (tid < off) sh[tid] += sh[tid + off]; __syncthreads(); }
    if (tid < 16) atomicAdd(&acc[tid], sh[tid]);
    __syncthreads();
    sh[tid] = s2; __syncthreads();
    for (int off = 128; off >= 16; off >>= 1) { if (tid < off) sh[tid] += sh[tid + off]; __syncthreads(); }
    if (tid < 16) atomicAdd(&acc[16 + tid], sh[tid]);
}

__global__ void bn_final(const float* acc, const float* g, const float* b,
                         float* coef, int n) {
    int c = threadIdx.x;
    if (c >= 16) return;
    float mu = acc[c] / (float)n;
    float var = acc[16 + c] / (float)n - mu * mu;
    float sc = g[c] / sqrtf(var + 1e-5f);
    coef[c] = sc;
    coef[16 + c] = b[c] - mu * sc;
}

// conv2 init: h = relu(bn(mean_k(P))); q2 = h @ w2_init ; root2 = h @ w2_root + b2
__global__ void conv2_init(const float* P, const float* coef, const float* w2i,
                           const float* w2r, const float* w2b,
                           float* q2, float* root2, int n) {
    unsigned node = blockIdx.x * blockDim.x + threadIdx.x;
    if (node >= (unsigned)n) return;
    const float* row = &P[node * 48u];
    float hb[16];
#pragma unroll
    for (int c = 0; c < 16; c++) {
        float h = (row[c] + row[16 + c] + row[32 + c]) * (1.f / 3.f);
        hb[c] = fmaxf(h * coef[c] + coef[16 + c], 0.f);
    }
#pragma unroll
    for (int k = 0; k < 3; k++) {
        float a = 0.f, r = 0.f;
#pragma unroll
        for (int c = 0; c < 16; c++) {
            a += hb[c] * w2i[k * 16 + c];
            r += hb[c] * w2r[k * 16 + c];
        }
        q2[node * 3u + k] = a;
        root2[node * 3u + k] = r + w2b[k];
    }
}

// conv2 aggregation: 3 channels, thread per node, no relu
__global__ void agg3(const float* q2, const float* root2, const int* row_ptr,
                     const int* csr_src, const float* csr_w, float* p2, int n) {
    unsigned node = blockIdx.x * blockDim.x + threadIdx.x;
    if (node >= (unsigned)n) return;
    int start = row_ptr[node], end = row_ptr[node + 1];
    float a0 = 0.f, a1 = 0.f, a2 = 0.f;
    for (int p = start; p < end; p++) {
        int s = csr_src[p];
        float w = csr_w[p];
        a0 += q2[(unsigned)s * 3u + 0] * w;
        a1 += q2[(unsigned)s * 3u + 1] * w;
        a2 += q2[(unsigned)s * 3u + 2] * w;
    }
    p2[node * 3u + 0] = a0 + root2[node * 3u + 0];
    p2[node * 3u + 1] = a1 + root2[node * 3u + 1];
    p2[node * 3u + 2] = a2 + root2[node * 3u + 2];
}

__global__ void transform2(const float* p2, const float* w2w, float* q2, int n3) {
    unsigned i = blockIdx.x * blockDim.x + threadIdx.x;
    if (i < (unsigned)n3) q2[i] = p2[i] * w2w[i % 3u];
}

__global__ void final_k(const float* p2, const float* lw, const float* lb,
                        float* out, int n) {
    unsigned i = blockIdx.x * blockDim.x + threadIdx.x;
    if (i >= (unsigned)n) return;
    float m = (p2[i * 3u] + p2[i * 3u + 1] + p2[i * 3u + 2]) * (1.f / 3.f);
    float v = m * lw[0] + lb[0];
    out[i] = 1.f / (1.f + expf(-v));
}

// ---------------- launch ----------------

extern "C" void kernel_launch(void* const* d_in, const int* in_sizes, int n_in,
                              void* d_out, int out_size, void* d_ws, size_t ws_size,
                              hipStream_t stream) {
    const float* x = (const float*)d_in[0];
    const int* ei = (const int*)d_in[1];          // int32 per harness convention
    const float* ew = (const float*)d_in[2];
    const float* w1_init = (const float*)d_in[3];
    const float* w1_w = (const float*)d_in[4];
    const float* w1_root = (const float*)d_in[5];
    const float* w1_b = (const float*)d_in[6];
    const float* bn1_g = (const float*)d_in[7];
    const float* bn1_b = (const float*)d_in[8];
    const float* w2_init = (const float*)d_in[9];
    const float* w2_w = (const float*)d_in[10];
    const float* w2_root = (const float*)d_in[11];
    const float* w2_b = (const float*)d_in[12];
    const float* lin_w = (const float*)d_in[13];
    const float* lin_b = (const float*)d_in[14];

    const int N = in_sizes[0];       // 100000
    const int E = in_sizes[2];       // 1600000
    float* out = (float*)d_out;

    // workspace layout (all 4-byte elems); total ~56 MB
    char* ws = (char*)d_ws;
    size_t off = 0;
    auto alloc = [&](size_t elems) { void* p = ws + off; off += elems * 4; return p; };
    float* degw    = (float*)alloc(N);        // becomes dis
    int*   cnt     = (int*)  alloc(N);
    int*   row_ptr = (int*)  alloc(N + 1);
    int*   cursor  = (int*)  alloc(N);
    int*   blockSums = (int*)alloc(128);
    float* bn_acc  = (float*)alloc(32);
    float* bn_coef = (float*)alloc(32);
    int*   csr_src = (int*)  alloc(E);
    float* csr_w   = (float*)alloc(E);
    float* bufP    = (float*)alloc((size_t)N * 48);
    float* bufQ    = (float*)alloc((size_t)N * 48);
    float* q2      = (float*)alloc((size_t)N * 3);
    float* p2      = (float*)alloc((size_t)N * 3);
    float* root2   = (float*)alloc((size_t)N * 3);
    (void)ws_size;

    const int BS = 256;
    int gE = (E + BS - 1) / BS;
    int gN = (N + BS - 1) / BS;

    // zero degw+cnt (adjacent) and bn_acc
    zero_kernel<<<(2 * N + BS - 1) / BS, BS, 0, stream>>>(degw, 2 * N);
    zero_kernel<<<1, 32, 0, stream>>>(bn_acc, 32);

    // degree + norm + CSR
    deg_kernel<<<gE, BS, 0, stream>>>(ei, ew, degw, cnt, E);
    dis_kernel<<<gN, BS, 0, stream>>>(degw, N);
    int nb = (N + 1023) / 1024;
    scan1<<<nb, 1024, 0, stream>>>(cnt, row_ptr, blockSums, N);
    scan2<<<1, 64, 0, stream>>>(blockSums, nb);
    scan3<<<nb, 1024, 0, stream>>>(row_ptr, cursor, blockSums, N, E);
    place_kernel<<<gE, BS, 0, stream>>>(ei, ew, degw, cursor, csr_src, csr_w, E);

    // ---- conv1 (K=3, H=16, T=4, relu) ----
    int g48 = (N * 48 + BS - 1) / BS;
    conv1_init<<<g48, BS, 0, stream>>>(x, w1_init, bufQ, N);
    int gAgg = (N + 3) / 4;  // 4 waves per 256-block, wave per node
    for (int t = 0; t < 4; t++) {
        if (t > 0) transform48<<<g48, BS, 0, stream>>>(bufP, w1_w, bufQ, N);
        agg48<<<gAgg, BS, 0, stream>>>(bufQ, x, w1_root, w1_b, row_ptr, csr_src, csr_w, bufP, N);
    }

    // ---- batchnorm (fused coefs) ----
    bn_stats<<<512, 256, 0, stream>>>(bufP, bn_acc, N);
    bn_final<<<1, 16, 0, stream>>>(bn_acc, bn1_g, bn1_b, bn_coef, N);

    // ---- conv2 (K=3, H=16->1, T=4, no act) ----
    conv2_init<<<gN, BS, 0, stream>>>(bufP, bn_coef, w2_init, w2_root, w2_b, q2, root2, N);
    for (int t = 0; t < 4; t++) {
        if (t > 0) transform2<<<(N * 3 + BS - 1) / BS, BS, 0, stream>>>(p2, w2_w, q2, N * 3);
        agg3<<<gN, BS, 0, stream>>>(q2, root2, row_ptr, csr_src, csr_w, p2, N);
    }

    // ---- final linear + sigmoid ----
    final_k<<<gN, BS, 0, stream>>>(p2, lin_w, lin_b, out, N);
}

// Round 3
// 594.078 us; speedup vs baseline: 1.7821x; 1.7821x over previous
//
#include <hip/hip_runtime.h>
#include <math.h>

// ---------------- setup kernels ----------------

__global__ void zero_kernel(float* p, int n) {
    int i = blockIdx.x * blockDim.x + threadIdx.x;
    if (i < n) p[i] = 0.f;
}

// weighted degree (for norm) + integer in-degree count (for CSR)
__global__ void deg_kernel(const int* ei, const float* ew,
                           float* degw, int* cnt, int E) {
    int i = blockIdx.x * blockDim.x + threadIdx.x;
    if (i >= E) return;
    int dst = ei[E + i];
    atomicAdd(&degw[dst], ew[i]);
    atomicAdd(&cnt[dst], 1);
}

__global__ void dis_kernel(float* degw, int n) {
    int i = blockIdx.x * blockDim.x + threadIdx.x;
    if (i < n) {
        float d = degw[i];
        degw[i] = (d > 0.f) ? (1.0f / sqrtf(d)) : 0.f;
    }
}

// --- 3-kernel exclusive scan of cnt -> row_ptr ---
__global__ void scan1(const int* cnt, int* row_ptr, int* blockSums, int n) {
    __shared__ int sh[1024];
    int i = blockIdx.x * 1024 + threadIdx.x;
    int v = (i < n) ? cnt[i] : 0;
    sh[threadIdx.x] = v;
    __syncthreads();
    for (int off = 1; off < 1024; off <<= 1) {
        int t = 0;
        if (threadIdx.x >= off) t = sh[threadIdx.x - off];
        __syncthreads();
        sh[threadIdx.x] += t;
        __syncthreads();
    }
    if (i < n) row_ptr[i] = sh[threadIdx.x] - v;
    if (threadIdx.x == 1023) blockSums[blockIdx.x] = sh[1023];
}

__global__ void scan2(int* blockSums, int nb) {
    if (threadIdx.x == 0 && blockIdx.x == 0) {
        int run = 0;
        for (int i = 0; i < nb; i++) { int v = blockSums[i]; blockSums[i] = run; run += v; }
    }
}

__global__ void scan3(int* row_ptr, int* cursor, const int* blockSums, int n, int E) {
    int i = blockIdx.x * 1024 + threadIdx.x;
    if (i < n) {
        int v = row_ptr[i] + blockSums[blockIdx.x];
        row_ptr[i] = v;
        cursor[i] = v;
    }
    if (i == 0) row_ptr[n] = E;
}

__global__ void place_kernel(const int* ei, const float* ew, const float* dis,
                             int* cursor, int* csr_src, float* csr_w, int E) {
    int i = blockIdx.x * blockDim.x + threadIdx.x;
    if (i >= E) return;
    int s = ei[i];
    int d = ei[E + i];
    float nrm = dis[s] * ew[i] * dis[d];
    int pos = atomicAdd(&cursor[d], 1);
    csr_src[pos] = s;
    csr_w[pos] = nrm;
}

// ---------------- conv1 ----------------

// rank-1 collapse of t=0: y[n] = sum_e norm_e * x[src_e]   (scalar gather, unroll 4)
__global__ void aggx(const float* __restrict__ x, const int* __restrict__ row_ptr,
                     const int* __restrict__ csr_src, const float* __restrict__ csr_w,
                     float* __restrict__ y, int n) {
    int node = blockIdx.x * blockDim.x + threadIdx.x;
    if (node >= n) return;
    int p = row_ptr[node], end = row_ptr[node + 1];
    float a0 = 0.f, a1 = 0.f, a2 = 0.f, a3 = 0.f;
    for (; p + 3 < end; p += 4) {
        int s0 = csr_src[p], s1 = csr_src[p + 1], s2 = csr_src[p + 2], s3 = csr_src[p + 3];
        float w0 = csr_w[p], w1 = csr_w[p + 1], w2 = csr_w[p + 2], w3 = csr_w[p + 3];
        a0 += x[s0] * w0; a1 += x[s1] * w1; a2 += x[s2] * w2; a3 += x[s3] * w3;
    }
    for (; p < end; p++) a0 += x[csr_src[p]] * csr_w[p];
    y[node] = (a0 + a1) + (a2 + a3);
}

// out_0 = relu(y*w_init + x*w_root + b)   (coalesced N*48 write)
__global__ void init48(const float* __restrict__ x, const float* __restrict__ y,
                       const float* __restrict__ w_init, const float* __restrict__ w_root,
                       const float* __restrict__ w_b, float* __restrict__ P, int n) {
    unsigned t = blockIdx.x * blockDim.x + threadIdx.x;
    if (t >= (unsigned)n * 48u) return;
    unsigned node = t / 48u, c = t % 48u;
    float v = y[node] * w_init[c] + x[node] * w_root[c] + w_b[c];
    P[t] = fmaxf(v, 0.f);
}

// fused step t>=1: P_out = relu( (A*P_in)*W + x*w_root + b )
// wave per node, lanes 0..47 own channels; W applied in-register via shfl.
__global__ void __launch_bounds__(256) agg48f(
    const float* __restrict__ P, const float* __restrict__ W,
    const float* __restrict__ x, const float* __restrict__ w_root,
    const float* __restrict__ w_b, const int* __restrict__ row_ptr,
    const int* __restrict__ csr_src, const float* __restrict__ csr_w,
    float* __restrict__ Pout, int n) {
    int wid = (int)((blockIdx.x * blockDim.x + threadIdx.x) >> 6);
    int lane = threadIdx.x & 63;
    if (wid >= n || lane >= 48) return;
    int k = lane >> 4, o = lane & 15;
    // preload W column: wv[i] = W[k][i][o]
    float wv[16];
#pragma unroll
    for (int i = 0; i < 16; i++) wv[i] = W[k * 256 + i * 16 + o];

    int p = row_ptr[wid], end = row_ptr[wid + 1];
    float a0 = 0.f, a1 = 0.f, a2 = 0.f, a3 = 0.f;
    for (; p + 3 < end; p += 4) {
        int s0 = csr_src[p], s1 = csr_src[p + 1], s2 = csr_src[p + 2], s3 = csr_src[p + 3];
        float w0 = csr_w[p], w1 = csr_w[p + 1], w2 = csr_w[p + 2], w3 = csr_w[p + 3];
        float q0 = P[(unsigned)s0 * 48u + lane];
        float q1 = P[(unsigned)s1 * 48u + lane];
        float q2 = P[(unsigned)s2 * 48u + lane];
        float q3 = P[(unsigned)s3 * 48u + lane];
        a0 += q0 * w0; a1 += q1 * w1; a2 += q2 * w2; a3 += q3 * w3;
    }
    for (; p < end; p++) a0 += P[(unsigned)csr_src[p] * 48u + lane] * csr_w[p];
    float S = (a0 + a1) + (a2 + a3);

    // in-register 16x16 transform: out[o] = sum_i S[i] * W[k][i][o]
    float acc = 0.f;
    int base = lane & 48;  // k*16
#pragma unroll
    for (int i = 0; i < 16; i++) {
        float sv = __shfl(S, base + i, 64);
        acc += sv * wv[i];
    }
    float v = acc + x[wid] * w_root[lane] + w_b[lane];
    Pout[(unsigned)wid * 48u + lane] = fmaxf(v, 0.f);
}

// ---------------- batchnorm ----------------

__global__ void bn_stats(const float* P, float* acc, int n) {
    int tid = threadIdx.x;
    int c = tid & 15;
    int rowSlot = (int)((blockIdx.x * blockDim.x + tid) >> 4);
    int rowStride = (int)((gridDim.x * blockDim.x) >> 4);
    float s1 = 0.f, s2 = 0.f;
    for (int r = rowSlot; r < n; r += rowStride) {
        const float* row = &P[(unsigned)r * 48u];
        float h = (row[c] + row[16 + c] + row[32 + c]) * (1.f / 3.f);
        s1 += h;
        s2 += h * h;
    }
    __shared__ float sh[256];
    sh[tid] = s1; __syncthreads();
    for (int off = 128; off >= 16; off >>= 1) { if (tid < off) sh[tid] += sh[tid + off]; __syncthreads(); }
    if (tid < 16) atomicAdd(&acc[tid], sh[tid]);
    __syncthreads();
    sh[tid] = s2; __syncthreads();
    for (int off = 128; off >= 16; off >>= 1) { if (tid < off) sh[tid] += sh[tid + off]; __syncthreads(); }
    if (tid < 16) atomicAdd(&acc[16 + tid], sh[tid]);
}

__global__ void bn_final(const float* acc, const float* g, const float* b,
                         float* coef, int n) {
    int c = threadIdx.x;
    if (c >= 16) return;
    float mu = acc[c] / (float)n;
    float var = acc[16 + c] / (float)n - mu * mu;
    float sc = g[c] / sqrtf(var + 1e-5f);
    coef[c] = sc;
    coef[16 + c] = b[c] - mu * sc;
}

// ---------------- conv2 (features padded to stride 4) ----------------

// h = relu(bn(mean_k(P))); q2 = h @ w2_init ; root2 = h @ w2_root + b2
__global__ void conv2_init(const float* __restrict__ P, const float* __restrict__ coef,
                           const float* __restrict__ w2i, const float* __restrict__ w2r,
                           const float* __restrict__ w2b,
                           float* __restrict__ q2, float* __restrict__ root2, int n) {
    unsigned node = blockIdx.x * blockDim.x + threadIdx.x;
    if (node >= (unsigned)n) return;
    const float* row = &P[node * 48u];
    float hb[16];
#pragma unroll
    for (int c = 0; c < 16; c++) {
        float h = (row[c] + row[16 + c] + row[32 + c]) * (1.f / 3.f);
        hb[c] = fmaxf(h * coef[c] + coef[16 + c], 0.f);
    }
    float qa[3], ra[3];
#pragma unroll
    for (int k = 0; k < 3; k++) {
        float a = 0.f, r = 0.f;
#pragma unroll
        for (int c = 0; c < 16; c++) {
            a += hb[c] * w2i[k * 16 + c];
            r += hb[c] * w2r[k * 16 + c];
        }
        qa[k] = a;
        ra[k] = r + w2b[k];
    }
    *(float4*)&q2[node * 4u]    = make_float4(qa[0], qa[1], qa[2], 0.f);
    *(float4*)&root2[node * 4u] = make_float4(ra[0], ra[1], ra[2], 0.f);
}

// fused conv2 step: S = A*Pin ; if APPLY_W: S *= w2w ; S += root2 ;
// if FINAL: out = sigmoid(mean(S)*lw + lb) else Pout = S
template<int APPLY_W, int FINAL>
__global__ void agg3f(const float* __restrict__ Pin, const float* __restrict__ w2w,
                      const float* __restrict__ root2,
                      const int* __restrict__ row_ptr, const int* __restrict__ csr_src,
                      const float* __restrict__ csr_w,
                      float* __restrict__ Pout, const float* __restrict__ lw,
                      const float* __restrict__ lb, int n) {
    int node = blockIdx.x * blockDim.x + threadIdx.x;
    if (node >= n) return;
    int p = row_ptr[node], end = row_ptr[node + 1];
    float a0 = 0.f, a1 = 0.f, a2 = 0.f;
    for (; p + 3 < end; p += 4) {
        int s0 = csr_src[p], s1 = csr_src[p + 1], s2 = csr_src[p + 2], s3 = csr_src[p + 3];
        float w0 = csr_w[p], w1 = csr_w[p + 1], w2 = csr_w[p + 2], w3 = csr_w[p + 3];
        float4 q0 = *(const float4*)&Pin[(unsigned)s0 * 4u];
        float4 q1 = *(const float4*)&Pin[(unsigned)s1 * 4u];
        float4 q2 = *(const float4*)&Pin[(unsigned)s2 * 4u];
        float4 q3 = *(const float4*)&Pin[(unsigned)s3 * 4u];
        a0 += q0.x * w0 + q1.x * w1 + q2.x * w2 + q3.x * w3;
        a1 += q0.y * w0 + q1.y * w1 + q2.y * w2 + q3.y * w3;
        a2 += q0.z * w0 + q1.z * w1 + q2.z * w2 + q3.z * w3;
    }
    for (; p < end; p++) {
        float4 q = *(const float4*)&Pin[(unsigned)csr_src[p] * 4u];
        float w = csr_w[p];
        a0 += q.x * w; a1 += q.y * w; a2 += q.z * w;
    }
    if (APPLY_W) { a0 *= w2w[0]; a1 *= w2w[1]; a2 *= w2w[2]; }
    a0 += root2[node * 4u + 0];
    a1 += root2[node * 4u + 1];
    a2 += root2[node * 4u + 2];
    if (FINAL) {
        float m = (a0 + a1 + a2) * (1.f / 3.f);
        float v = m * lw[0] + lb[0];
        Pout[node] = 1.f / (1.f + expf(-v));
    } else {
        *(float4*)&Pout[node * 4u] = make_float4(a0, a1, a2, 0.f);
    }
}

// ---------------- launch ----------------

extern "C" void kernel_launch(void* const* d_in, const int* in_sizes, int n_in,
                              void* d_out, int out_size, void* d_ws, size_t ws_size,
                              hipStream_t stream) {
    const float* x = (const float*)d_in[0];
    const int* ei = (const int*)d_in[1];          // int32 per harness convention
    const float* ew = (const float*)d_in[2];
    const float* w1_init = (const float*)d_in[3];
    const float* w1_w = (const float*)d_in[4];
    const float* w1_root = (const float*)d_in[5];
    const float* w1_b = (const float*)d_in[6];
    const float* bn1_g = (const float*)d_in[7];
    const float* bn1_b = (const float*)d_in[8];
    const float* w2_init = (const float*)d_in[9];
    const float* w2_w = (const float*)d_in[10];
    const float* w2_root = (const float*)d_in[11];
    const float* w2_b = (const float*)d_in[12];
    const float* lin_w = (const float*)d_in[13];
    const float* lin_b = (const float*)d_in[14];

    const int N = in_sizes[0];       // 100000
    const int E = in_sizes[2];       // 1600000
    float* out = (float*)d_out;

    // workspace layout (all 4-byte elems, offsets rounded to 16B)
    char* ws = (char*)d_ws;
    size_t off = 0;
    auto alloc = [&](size_t elems) {
        void* p = ws + off;
        off += ((elems + 3) & ~(size_t)3) * 4;
        return p;
    };
    float* degw      = (float*)alloc(N);        // becomes dis
    int*   cnt       = (int*)  alloc(N);
    int*   row_ptr   = (int*)  alloc(N + 1);
    int*   cursor    = (int*)  alloc(N);
    int*   blockSums = (int*)  alloc(128);
    float* bn_acc    = (float*)alloc(32);
    float* bn_coef   = (float*)alloc(32);
    int*   csr_src   = (int*)  alloc(E);
    float* csr_w     = (float*)alloc(E);
    float* bufP      = (float*)alloc((size_t)N * 48);
    float* bufQ      = (float*)alloc((size_t)N * 48);
    float* y1        = (float*)alloc(N);
    float* q2        = (float*)alloc((size_t)N * 4);
    float* root2     = (float*)alloc((size_t)N * 4);
    float* p2a       = (float*)alloc((size_t)N * 4);
    float* p2b       = (float*)alloc((size_t)N * 4);
    (void)ws_size;

    const int BS = 256;
    int gE = (E + BS - 1) / BS;
    int gN = (N + BS - 1) / BS;

    zero_kernel<<<(2 * N + BS - 1) / BS, BS, 0, stream>>>(degw, 2 * N);  // degw+cnt adjacent
    zero_kernel<<<1, 32, 0, stream>>>(bn_acc, 32);

    // degree + norm + CSR
    deg_kernel<<<gE, BS, 0, stream>>>(ei, ew, degw, cnt, E);
    dis_kernel<<<gN, BS, 0, stream>>>(degw, N);
    int nb = (N + 1023) / 1024;
    scan1<<<nb, 1024, 0, stream>>>(cnt, row_ptr, blockSums, N);
    scan2<<<1, 64, 0, stream>>>(blockSums, nb);
    scan3<<<nb, 1024, 0, stream>>>(row_ptr, cursor, blockSums, N, E);
    place_kernel<<<gE, BS, 0, stream>>>(ei, ew, degw, cursor, csr_src, csr_w, E);

    // ---- conv1 (K=3, H=16, T=4, relu) ----
    // t=0 via rank-1 collapse: scalar gather + broadcast init
    aggx<<<gN, BS, 0, stream>>>(x, row_ptr, csr_src, csr_w, y1, N);
    int g48 = (N * 48 + BS - 1) / BS;
    init48<<<g48, BS, 0, stream>>>(x, y1, w1_init, w1_root, w1_b, bufP, N);
    // t=1..3 fused aggregate+transform (A*(P*W) == (A*P)*W)
    int gAgg = (N + 3) / 4;  // wave per node
    agg48f<<<gAgg, BS, 0, stream>>>(bufP, w1_w, x, w1_root, w1_b, row_ptr, csr_src, csr_w, bufQ, N);
    agg48f<<<gAgg, BS, 0, stream>>>(bufQ, w1_w, x, w1_root, w1_b, row_ptr, csr_src, csr_w, bufP, N);
    agg48f<<<gAgg, BS, 0, stream>>>(bufP, w1_w, x, w1_root, w1_b, row_ptr, csr_src, csr_w, bufQ, N);
    // conv1 output now in bufQ

    // ---- batchnorm (fused coefs) ----
    bn_stats<<<512, 256, 0, stream>>>(bufQ, bn_acc, N);
    bn_final<<<1, 16, 0, stream>>>(bn_acc, bn1_g, bn1_b, bn_coef, N);

    // ---- conv2 (K=3, H=16->1, T=4, no act) ----
    conv2_init<<<gN, BS, 0, stream>>>(bufQ, bn_coef, w2_init, w2_root, w2_b, q2, root2, N);
    agg3f<0, 0><<<gN, BS, 0, stream>>>(q2,  w2_w, root2, row_ptr, csr_src, csr_w, p2a, lin_w, lin_b, N);
    agg3f<1, 0><<<gN, BS, 0, stream>>>(p2a, w2_w, root2, row_ptr, csr_src, csr_w, p2b, lin_w, lin_b, N);
    agg3f<1, 0><<<gN, BS, 0, stream>>>(p2b, w2_w, root2, row_ptr, csr_src, csr_w, p2a, lin_w, lin_b, N);
    agg3f<1, 1><<<gN, BS, 0, stream>>>(p2a, w2_w, root2, row_ptr, csr_src, csr_w, out, lin_w, lin_b, N);
}

// Round 4
// 446.067 us; speedup vs baseline: 2.3734x; 1.3318x over previous
//
#include <hip/hip_runtime.h>
#include <hip/hip_bf16.h>
#include <math.h>

// ---------------- setup kernels ----------------

__global__ void zero_kernel(float* p, int n) {
    int i = blockIdx.x * blockDim.x + threadIdx.x;
    if (i < n) p[i] = 0.f;
}

// single-atomic histogram: rank[i] = old count of dst
__global__ void rank_kernel(const int* __restrict__ ei, int* __restrict__ cnt,
                            int* __restrict__ rank, int E) {
    int i = blockIdx.x * blockDim.x + threadIdx.x;
    if (i >= E) return;
    int dst = ei[E + i];
    rank[i] = atomicAdd(&cnt[dst], 1);
}

// --- 3-kernel exclusive scan of cnt -> row_ptr ---
__global__ void scan1(const int* cnt, int* row_ptr, int* blockSums, int n) {
    __shared__ int sh[1024];
    int i = blockIdx.x * 1024 + threadIdx.x;
    int v = (i < n) ? cnt[i] : 0;
    sh[threadIdx.x] = v;
    __syncthreads();
    for (int off = 1; off < 1024; off <<= 1) {
        int t = 0;
        if (threadIdx.x >= off) t = sh[threadIdx.x - off];
        __syncthreads();
        sh[threadIdx.x] += t;
        __syncthreads();
    }
    if (i < n) row_ptr[i] = sh[threadIdx.x] - v;
    if (threadIdx.x == 1023) blockSums[blockIdx.x] = sh[1023];
}

__global__ void scan2(int* blockSums, int nb) {
    if (threadIdx.x == 0 && blockIdx.x == 0) {
        int run = 0;
        for (int i = 0; i < nb; i++) { int v = blockSums[i]; blockSums[i] = run; run += v; }
    }
}

__global__ void scan3(int* row_ptr, const int* blockSums, int n, int E) {
    int i = blockIdx.x * 1024 + threadIdx.x;
    if (i < n) row_ptr[i] += blockSums[blockIdx.x];
    if (i == 0) row_ptr[n] = E;
}

// place edges: pos = row_ptr[dst] + rank[i]; single 8B scattered store (src, ew)
__global__ void place2(const int* __restrict__ ei, const float* __restrict__ ew,
                       const int* __restrict__ rank, const int* __restrict__ row_ptr,
                       int2* __restrict__ csr, int E) {
    int i = blockIdx.x * blockDim.x + threadIdx.x;
    if (i >= E) return;
    int s = ei[i];
    int d = ei[E + i];
    int pos = row_ptr[d] + rank[i];
    csr[pos] = make_int2(s, __float_as_int(ew[i]));
}

// weighted degree from CSR (no atomics) -> dis = 1/sqrt(deg)
__global__ void wdeg_dis(const int2* __restrict__ csr, const int* __restrict__ row_ptr,
                         float* __restrict__ dis, int n) {
    int node = blockIdx.x * blockDim.x + threadIdx.x;
    if (node >= n) return;
    int p = row_ptr[node], end = row_ptr[node + 1];
    float s = 0.f;
    for (; p < end; p++) s += __int_as_float(csr[p].y);
    dis[node] = (s > 0.f) ? (1.0f / sqrtf(s)) : 0.f;
}

// csr.y <- dis[dst]*dis[src]*ew   (in place)
__global__ void normk(int2* __restrict__ csr, const int* __restrict__ row_ptr,
                      const float* __restrict__ dis, int n) {
    int node = blockIdx.x * blockDim.x + threadIdx.x;
    if (node >= n) return;
    int p = row_ptr[node], end = row_ptr[node + 1];
    float dn = dis[node];
    for (; p < end; p++) {
        int2 e = csr[p];
        csr[p].y = __float_as_int(__int_as_float(e.y) * dn * dis[e.x]);
    }
}

// ---------------- conv1 (bf16 features, row stride 64) ----------------

// rank-1 collapse of t=0: y[n] = sum_e norm_e * x[src_e]
__global__ void aggx(const float* __restrict__ x, const int* __restrict__ row_ptr,
                     const int2* __restrict__ csr, float* __restrict__ y, int n) {
    int node = blockIdx.x * blockDim.x + threadIdx.x;
    if (node >= n) return;
    int p = row_ptr[node], end = row_ptr[node + 1];
    float a0 = 0.f, a1 = 0.f, a2 = 0.f, a3 = 0.f, a4 = 0.f, a5 = 0.f, a6 = 0.f, a7 = 0.f;
    for (; p + 7 < end; p += 8) {
        int2 e0 = csr[p], e1 = csr[p+1], e2 = csr[p+2], e3 = csr[p+3];
        int2 e4 = csr[p+4], e5 = csr[p+5], e6 = csr[p+6], e7 = csr[p+7];
        a0 += x[e0.x] * __int_as_float(e0.y);
        a1 += x[e1.x] * __int_as_float(e1.y);
        a2 += x[e2.x] * __int_as_float(e2.y);
        a3 += x[e3.x] * __int_as_float(e3.y);
        a4 += x[e4.x] * __int_as_float(e4.y);
        a5 += x[e5.x] * __int_as_float(e5.y);
        a6 += x[e6.x] * __int_as_float(e6.y);
        a7 += x[e7.x] * __int_as_float(e7.y);
    }
    for (; p + 1 < end; p += 2) {
        int2 e0 = csr[p], e1 = csr[p+1];
        a0 += x[e0.x] * __int_as_float(e0.y);
        a1 += x[e1.x] * __int_as_float(e1.y);
    }
    if (p < end) { int2 e = csr[p]; a0 += x[e.x] * __int_as_float(e.y); }
    y[node] = ((a0 + a1) + (a2 + a3)) + ((a4 + a5) + (a6 + a7));
}

// out_0 = relu(y*w_init + x*w_root + b), bf16, pad channels 48..63 with 0
__global__ void init48(const float* __restrict__ x, const float* __restrict__ y,
                       const float* __restrict__ w_init, const float* __restrict__ w_root,
                       const float* __restrict__ w_b, __hip_bfloat16* __restrict__ P, int n) {
    unsigned t = blockIdx.x * blockDim.x + threadIdx.x;
    if (t >= (unsigned)n * 64u) return;
    unsigned node = t >> 6, c = t & 63;
    float v = 0.f;
    if (c < 48) v = fmaxf(y[node] * w_init[c] + x[node] * w_root[c] + w_b[c], 0.f);
    P[t] = __float2bfloat16(v);
}

// fused step t>=1: P_out = relu( (A*P_in)*W + x*w_root + b )
// wave per node; lanes 0..47 own channels; W applied in-register via shfl.
__global__ void __launch_bounds__(256) agg48f(
    const __hip_bfloat16* __restrict__ P, const float* __restrict__ W,
    const float* __restrict__ x, const float* __restrict__ w_root,
    const float* __restrict__ w_b, const int* __restrict__ row_ptr,
    const int2* __restrict__ csr, __hip_bfloat16* __restrict__ Pout, int n) {
    int wid = (int)((blockIdx.x * blockDim.x + threadIdx.x) >> 6);
    int lane = threadIdx.x & 63;
    if (wid >= n) return;
    unsigned orow = (unsigned)wid * 64u;
    if (lane >= 48) { Pout[orow + lane] = __float2bfloat16(0.f); return; }
    int k = lane >> 4, o = lane & 15;
    float wv[16];
#pragma unroll
    for (int i = 0; i < 16; i++) wv[i] = W[k * 256 + i * 16 + o];

    int p = row_ptr[wid], end = row_ptr[wid + 1];
    float a0 = 0.f, a1 = 0.f, a2 = 0.f, a3 = 0.f, a4 = 0.f, a5 = 0.f, a6 = 0.f, a7 = 0.f;
    for (; p + 7 < end; p += 8) {
        int2 e0 = csr[p], e1 = csr[p+1], e2 = csr[p+2], e3 = csr[p+3];
        int2 e4 = csr[p+4], e5 = csr[p+5], e6 = csr[p+6], e7 = csr[p+7];
        float q0 = __bfloat162float(P[(unsigned)e0.x * 64u + lane]);
        float q1 = __bfloat162float(P[(unsigned)e1.x * 64u + lane]);
        float q2 = __bfloat162float(P[(unsigned)e2.x * 64u + lane]);
        float q3 = __bfloat162float(P[(unsigned)e3.x * 64u + lane]);
        float q4 = __bfloat162float(P[(unsigned)e4.x * 64u + lane]);
        float q5 = __bfloat162float(P[(unsigned)e5.x * 64u + lane]);
        float q6 = __bfloat162float(P[(unsigned)e6.x * 64u + lane]);
        float q7 = __bfloat162float(P[(unsigned)e7.x * 64u + lane]);
        a0 += q0 * __int_as_float(e0.y);
        a1 += q1 * __int_as_float(e1.y);
        a2 += q2 * __int_as_float(e2.y);
        a3 += q3 * __int_as_float(e3.y);
        a4 += q4 * __int_as_float(e4.y);
        a5 += q5 * __int_as_float(e5.y);
        a6 += q6 * __int_as_float(e6.y);
        a7 += q7 * __int_as_float(e7.y);
    }
    for (; p + 1 < end; p += 2) {
        int2 e0 = csr[p], e1 = csr[p+1];
        a0 += __bfloat162float(P[(unsigned)e0.x * 64u + lane]) * __int_as_float(e0.y);
        a1 += __bfloat162float(P[(unsigned)e1.x * 64u + lane]) * __int_as_float(e1.y);
    }
    if (p < end) {
        int2 e = csr[p];
        a0 += __bfloat162float(P[(unsigned)e.x * 64u + lane]) * __int_as_float(e.y);
    }
    float S = ((a0 + a1) + (a2 + a3)) + ((a4 + a5) + (a6 + a7));

    // in-register 16x16 transform: out[o] = sum_i S[i] * W[k][i][o]
    float acc = 0.f;
    int base = lane & 48;  // k*16
#pragma unroll
    for (int i = 0; i < 16; i++) {
        float sv = __shfl(S, base + i, 64);
        acc += sv * wv[i];
    }
    float v = acc + x[wid] * w_root[lane] + w_b[lane];
    Pout[orow + lane] = __float2bfloat16(fmaxf(v, 0.f));
}

// ---------------- batchnorm ----------------

__global__ void bn_stats(const __hip_bfloat16* __restrict__ P, float* __restrict__ acc, int n) {
    int tid = threadIdx.x;
    int c = tid & 15;
    int rowSlot = (int)((blockIdx.x * blockDim.x + tid) >> 4);
    int rowStride = (int)((gridDim.x * blockDim.x) >> 4);
    float s1 = 0.f, s2 = 0.f;
    for (int r = rowSlot; r < n; r += rowStride) {
        const __hip_bfloat16* row = &P[(unsigned)r * 64u];
        float h = (__bfloat162float(row[c]) + __bfloat162float(row[16 + c]) +
                   __bfloat162float(row[32 + c])) * (1.f / 3.f);
        s1 += h;
        s2 += h * h;
    }
    __shared__ float sh[256];
    sh[tid] = s1; __syncthreads();
    for (int off = 128; off >= 16; off >>= 1) { if (tid < off) sh[tid] += sh[tid + off]; __syncthreads(); }
    if (tid < 16) atomicAdd(&acc[tid], sh[tid]);
    __syncthreads();
    sh[tid] = s2; __syncthreads();
    for (int off = 128; off >= 16; off >>= 1) { if (tid < off) sh[tid] += sh[tid + off]; __syncthreads(); }
    if (tid < 16) atomicAdd(&acc[16 + tid], sh[tid]);
}

__global__ void bn_final(const float* acc, const float* g, const float* b,
                         float* coef, int n) {
    int c = threadIdx.x;
    if (c >= 16) return;
    float mu = acc[c] / (float)n;
    float var = acc[16 + c] / (float)n - mu * mu;
    float sc = g[c] / sqrtf(var + 1e-5f);
    coef[c] = sc;
    coef[16 + c] = b[c] - mu * sc;
}

// ---------------- conv2: linear => Horner collapse ----------------
// h2 = A^4 u~ + A^3 r3~ + A^2 r2~ + A r1~ + r0~
// u~ = (1/3) sum_k w_k^3 h.w2i_k ; rj~ = h.rho_j + beta_j

__global__ void cvec_prep(const float* __restrict__ w2w, const float* __restrict__ w2i,
                          const float* __restrict__ w2r, const float* __restrict__ w2b,
                          float* __restrict__ cvec) {
    int c = threadIdx.x;
    float wk0 = w2w[0], wk1 = w2w[1], wk2 = w2w[2];
    const float inv3 = 1.f / 3.f;
    if (c < 16) {
        float psi = 0.f, r3 = 0.f, r2 = 0.f, r1 = 0.f, r0 = 0.f;
        float wks[3] = {wk0, wk1, wk2};
#pragma unroll
        for (int k = 0; k < 3; k++) {
            float w = wks[k], w2_ = w * w, w3 = w2_ * w;
            psi += w3 * w2i[k * 16 + c];
            float rr = w2r[k * 16 + c];
            r3 += w3 * rr; r2 += w2_ * rr; r1 += w * rr; r0 += rr;
        }
        cvec[c] = psi * inv3;
        cvec[16 + c] = r3 * inv3;
        cvec[32 + c] = r2 * inv3;
        cvec[48 + c] = r1 * inv3;
        cvec[64 + c] = r0 * inv3;
    } else if (c == 16) {
        float b3 = 0.f, b2 = 0.f, b1 = 0.f, b0 = 0.f;
        float wks[3] = {wk0, wk1, wk2};
#pragma unroll
        for (int k = 0; k < 3; k++) {
            float w = wks[k], w2_ = w * w, w3 = w2_ * w;
            float b = w2b[k];
            b3 += w3 * b; b2 += w2_ * b; b1 += w * b; b0 += b;
        }
        cvec[80] = b3 * inv3; cvec[81] = b2 * inv3; cvec[82] = b1 * inv3; cvec[83] = b0 * inv3;
    }
}

// per node: h = relu(bn(mean_k P)); z = h.psi ; R = {h.rho3+b3, h.rho2+b2, h.rho1+b1, h.rho0+b0}
__global__ void conv2_init(const __hip_bfloat16* __restrict__ P, const float* __restrict__ coef,
                           const float* __restrict__ cvec,
                           float* __restrict__ z, float4* __restrict__ R, int n) {
    unsigned node = blockIdx.x * blockDim.x + threadIdx.x;
    if (node >= (unsigned)n) return;
    const __hip_bfloat16* row = &P[node * 64u];
    float zz = 0.f, r3 = cvec[80], r2 = cvec[81], r1 = cvec[82], r0 = cvec[83];
#pragma unroll
    for (int c = 0; c < 16; c++) {
        float h = (__bfloat162float(row[c]) + __bfloat162float(row[16 + c]) +
                   __bfloat162float(row[32 + c])) * (1.f / 3.f);
        float hb = fmaxf(h * coef[c] + coef[16 + c], 0.f);
        zz += hb * cvec[c];
        r3 += hb * cvec[16 + c];
        r2 += hb * cvec[32 + c];
        r1 += hb * cvec[48 + c];
        r0 += hb * cvec[64 + c];
    }
    z[node] = zz;
    R[node] = make_float4(r3, r2, r1, r0);
}

// Horner step: zout = A*zin + R[:,comp] ; FINAL: out = sigmoid((A*zin + R)*lw + lb)
template<int FINAL>
__global__ void horner(const float* __restrict__ zin, const float* __restrict__ R, int comp,
                       const int* __restrict__ row_ptr, const int2* __restrict__ csr,
                       float* __restrict__ zout, const float* __restrict__ lw,
                       const float* __restrict__ lb, int n) {
    int node = blockIdx.x * blockDim.x + threadIdx.x;
    if (node >= n) return;
    int p = row_ptr[node], end = row_ptr[node + 1];
    float a0 = 0.f, a1 = 0.f, a2 = 0.f, a3 = 0.f, a4 = 0.f, a5 = 0.f, a6 = 0.f, a7 = 0.f;
    for (; p + 7 < end; p += 8) {
        int2 e0 = csr[p], e1 = csr[p+1], e2 = csr[p+2], e3 = csr[p+3];
        int2 e4 = csr[p+4], e5 = csr[p+5], e6 = csr[p+6], e7 = csr[p+7];
        a0 += zin[e0.x] * __int_as_float(e0.y);
        a1 += zin[e1.x] * __int_as_float(e1.y);
        a2 += zin[e2.x] * __int_as_float(e2.y);
        a3 += zin[e3.x] * __int_as_float(e3.y);
        a4 += zin[e4.x] * __int_as_float(e4.y);
        a5 += zin[e5.x] * __int_as_float(e5.y);
        a6 += zin[e6.x] * __int_as_float(e6.y);
        a7 += zin[e7.x] * __int_as_float(e7.y);
    }
    for (; p + 1 < end; p += 2) {
        int2 e0 = csr[p], e1 = csr[p+1];
        a0 += zin[e0.x] * __int_as_float(e0.y);
        a1 += zin[e1.x] * __int_as_float(e1.y);
    }
    if (p < end) { int2 e = csr[p]; a0 += zin[e.x] * __int_as_float(e.y); }
    float v = ((a0 + a1) + (a2 + a3)) + ((a4 + a5) + (a6 + a7)) + R[(unsigned)node * 4u + comp];
    if (FINAL) {
        float t = v * lw[0] + lb[0];
        zout[node] = 1.f / (1.f + expf(-t));
    } else {
        zout[node] = v;
    }
}

// ---------------- launch ----------------

extern "C" void kernel_launch(void* const* d_in, const int* in_sizes, int n_in,
                              void* d_out, int out_size, void* d_ws, size_t ws_size,
                              hipStream_t stream) {
    const float* x = (const float*)d_in[0];
    const int* ei = (const int*)d_in[1];          // int32 per harness convention
    const float* ew = (const float*)d_in[2];
    const float* w1_init = (const float*)d_in[3];
    const float* w1_w = (const float*)d_in[4];
    const float* w1_root = (const float*)d_in[5];
    const float* w1_b = (const float*)d_in[6];
    const float* bn1_g = (const float*)d_in[7];
    const float* bn1_b = (const float*)d_in[8];
    const float* w2_init = (const float*)d_in[9];
    const float* w2_w = (const float*)d_in[10];
    const float* w2_root = (const float*)d_in[11];
    const float* w2_b = (const float*)d_in[12];
    const float* lin_w = (const float*)d_in[13];
    const float* lin_b = (const float*)d_in[14];

    const int N = in_sizes[0];       // 100000
    const int E = in_sizes[2];       // 1600000
    float* out = (float*)d_out;

    // workspace layout (16B-aligned chunks); total ~43 MB
    char* ws = (char*)d_ws;
    size_t off = 0;
    auto alloc = [&](size_t bytes) {
        void* p = ws + off;
        off += (bytes + 15) & ~(size_t)15;
        return p;
    };
    int*   cnt       = (int*)  alloc((size_t)N * 4);
    int*   row_ptr   = (int*)  alloc((size_t)(N + 1) * 4);
    int*   blockSums = (int*)  alloc(128 * 4);
    float* bn_acc    = (float*)alloc(32 * 4);
    float* bn_coef   = (float*)alloc(32 * 4);
    float* cvec      = (float*)alloc(96 * 4);
    float* dis       = (float*)alloc((size_t)N * 4);
    float* y1        = (float*)alloc((size_t)N * 4);
    float* zA        = (float*)alloc((size_t)N * 4);
    float* zB        = (float*)alloc((size_t)N * 4);
    float4* Rbuf     = (float4*)alloc((size_t)N * 16);
    int2*  csr       = (int2*) alloc((size_t)E * 8);
    __hip_bfloat16* bufP = (__hip_bfloat16*)alloc((size_t)N * 64 * 2);
    __hip_bfloat16* bufQ = (__hip_bfloat16*)alloc((size_t)N * 64 * 2);
    int* rank = (int*)bufP;   // overlay: rank[] dead before bufP first written
    (void)ws_size;

    const int BS = 256;
    int gE = (E + BS - 1) / BS;
    int gN = (N + BS - 1) / BS;

    zero_kernel<<<gN, BS, 0, stream>>>((float*)cnt, N);
    zero_kernel<<<1, 32, 0, stream>>>(bn_acc, 32);

    // CSR build: one atomic per edge total
    rank_kernel<<<gE, BS, 0, stream>>>(ei, cnt, rank, E);
    int nb = (N + 1023) / 1024;
    scan1<<<nb, 1024, 0, stream>>>(cnt, row_ptr, blockSums, N);
    scan2<<<1, 64, 0, stream>>>(blockSums, nb);
    scan3<<<nb, 1024, 0, stream>>>(row_ptr, blockSums, N, E);
    place2<<<gE, BS, 0, stream>>>(ei, ew, rank, row_ptr, csr, E);
    wdeg_dis<<<gN, BS, 0, stream>>>(csr, row_ptr, dis, N);
    normk<<<gN, BS, 0, stream>>>(csr, row_ptr, dis, N);

    // ---- conv1 (K=3, H=16, T=4, relu), bf16 features ----
    aggx<<<gN, BS, 0, stream>>>(x, row_ptr, csr, y1, N);
    int g64 = (N * 64 + BS - 1) / BS;
    init48<<<g64, BS, 0, stream>>>(x, y1, w1_init, w1_root, w1_b, bufP, N);
    int gAgg = (N + 3) / 4;  // wave per node
    agg48f<<<gAgg, BS, 0, stream>>>(bufP, w1_w, x, w1_root, w1_b, row_ptr, csr, bufQ, N);
    agg48f<<<gAgg, BS, 0, stream>>>(bufQ, w1_w, x, w1_root, w1_b, row_ptr, csr, bufP, N);
    agg48f<<<gAgg, BS, 0, stream>>>(bufP, w1_w, x, w1_root, w1_b, row_ptr, csr, bufQ, N);
    // conv1 output in bufQ

    // ---- batchnorm (fused coefs) ----
    bn_stats<<<512, 256, 0, stream>>>(bufQ, bn_acc, N);
    bn_final<<<1, 16, 0, stream>>>(bn_acc, bn1_g, bn1_b, bn_coef, N);

    // ---- conv2 collapsed to scalar Horner chain ----
    cvec_prep<<<1, 64, 0, stream>>>(w2_w, w2_init, w2_root, w2_b, cvec);
    conv2_init<<<gN, BS, 0, stream>>>(bufQ, bn_coef, cvec, zA, Rbuf, N);
    horner<0><<<gN, BS, 0, stream>>>(zA, (const float*)Rbuf, 0, row_ptr, csr, zB, lin_w, lin_b, N);
    horner<0><<<gN, BS, 0, stream>>>(zB, (const float*)Rbuf, 1, row_ptr, csr, zA, lin_w, lin_b, N);
    horner<0><<<gN, BS, 0, stream>>>(zA, (const float*)Rbuf, 2, row_ptr, csr, zB, lin_w, lin_b, N);
    horner<1><<<gN, BS, 0, stream>>>(zB, (const float*)Rbuf, 3, row_ptr, csr, out, lin_w, lin_b, N);
}